// Round 1
// baseline (479.224 us; speedup 1.0000x reference)
//
#include <hip/hip_runtime.h>
#include <stdint.h>
#include <math.h>

typedef unsigned short u16;
typedef __bf16 bf16x8 __attribute__((ext_vector_type(8)));
typedef float f32x4 __attribute__((ext_vector_type(4)));

#define NEG_ -10000.0f

__device__ __forceinline__ u16 f2bf(float f){
  unsigned u = __float_as_uint(f);
  unsigned r = (u + 0x7fffu + ((u >> 16) & 1u)) >> 16;
  return (u16)r;
}

__device__ __forceinline__ float gelu_exact(float v){
  return 0.5f * v * (1.f + erff(v * 0.70710678118654752f));
}
__device__ __forceinline__ float sigmoidf_(float z){ return 1.f / (1.f + expf(-z)); }

__device__ __forceinline__ void async_load16(const void* g, void* lds){
  typedef const __attribute__((address_space(1))) unsigned int* gp_t;
  typedef __attribute__((address_space(3))) unsigned int* lp_t;
  __builtin_amdgcn_global_load_lds((gp_t)(uintptr_t)g, (lp_t)(uintptr_t)lds, 16, 0, 0);
}

// ---------------- gates + padded bias ----------------
__global__ __launch_bounds__(256) void prep_gates(
    const float* __restrict__ s, const int* __restrict__ t,
    const float* __restrict__ efc1, const float* __restrict__ efc2,
    const float* __restrict__ elarger, const float* __restrict__ fc1_b,
    float* __restrict__ gfc1p, float* __restrict__ b1p,
    float* __restrict__ gfc2, float* __restrict__ glarger)
{
  int i = blockIdx.x * 256 + threadIdx.x;
  float sv = s[0]; int tt = t[0];
  if (i < 2048){
    float g = 0.f, b = 0.f;
    if (i < 2000){ g = sigmoidf_(sv * efc1[tt * 2000 + i]); b = fc1_b[i]; }
    gfc1p[i] = g; b1p[i] = b;
  }
  if (i < 768){
    gfc2[i]    = sigmoidf_(sv * efc2[tt * 768 + i]);
    glarger[i] = sigmoidf_(sv * elarger[tt * 768 + i]);
  }
}

// ---------------- weight conversions (zero-padded) ----------------
__global__ __launch_bounds__(256) void conv_w1(const float* __restrict__ fc1_w, u16* __restrict__ Bw1){
  int idx = blockIdx.x * 256 + threadIdx.x;            // [2048][768]
  if (idx >= 2048 * 768) return;
  int n = idx / 768, k = idx % 768;
  float v = (n < 2000) ? fc1_w[n * 768 + k] : 0.f;
  Bw1[idx] = f2bf(v);
}
__global__ __launch_bounds__(256) void conv_w2(const float* __restrict__ fc2_w, u16* __restrict__ Bw2){
  int idx = blockIdx.x * 256 + threadIdx.x;            // [768][2048]
  if (idx >= 768 * 2048) return;
  int h = idx / 2048, k = idx % 2048;
  float v = (k < 2000) ? fc2_w[h * 2000 + k] : 0.f;
  Bw2[idx] = f2bf(v);
}

// ---------------- sem capsules + squash + priors + dynamic routing ----------------
// one block = 8 tokens; vote stored m-major [3][16384][3] so h_caps reshape is a flat view
__global__ __launch_bounds__(256) void sem_route(
    const float* __restrict__ x, const int* __restrict__ t_ptr,
    const float* __restrict__ sem_w, const float* __restrict__ sem_b,
    const float* __restrict__ rw, float* __restrict__ voteflat)
{
  __shared__ float xs[8][772];   // +4 pad: rows land on distinct banks
  __shared__ float semv[8][32];  // 30 used, flat order c*10+t  (== x5 flat order r*3+c2)
  const int tid = threadIdx.x;
  const int n0 = blockIdx.x * 8;
  const float4* xg = (const float4*)(x + (size_t)n0 * 768);
  for (int i = tid; i < 1536; i += 256){
    int r = i / 192, q = i % 192;
    ((float4*)&xs[r][0])[q] = xg[(size_t)r * 192 + q];
  }
  __syncthreads();
  const int row = tid / 30, dd = tid % 30;
  if (row < 8){
    const int c = dd / 10, tt2 = dd % 10;
    const float4* wr = (const float4*)(sem_w + (size_t)(tt2 * 3 + c) * 768);
    const float4* xr = (const float4*)&xs[row][0];
    float acc = 0.f;
#pragma unroll 4
    for (int q = 0; q < 192; q++){
      float4 a = xr[q], b = wr[q];
      acc += a.x * b.x + a.y * b.y + a.z * b.z + a.w * b.w;
    }
    semv[row][dd] = acc + sem_b[tt2 * 3 + c];
  }
  __syncthreads();
  if (tid < 24){ // squash over t per (row, c)
    const int r2 = tid / 3, c = tid % 3;
    float v[10]; float sq = 0.f;
#pragma unroll
    for (int j = 0; j < 10; j++){ v[j] = semv[r2][c * 10 + j]; sq += v[j] * v[j]; }
    sq += 1e-16f;
    const float scale = (sq / (1.f + sq)) / sqrtf(sq);
#pragma unroll
    for (int j = 0; j < 10; j++) semv[r2][c * 10 + j] = v[j] * scale;
  }
  __syncthreads();
  if (tid < 24){ // routing per (row, m)
    const int r2 = tid / 3, m = tid % 3;
    const int tt = t_ptr[0];
    float p[10][3];
#pragma unroll
    for (int r = 0; r < 10; r++){
      const float x0 = semv[r2][r * 3 + 0], x1 = semv[r2][r * 3 + 1], x2 = semv[r2][r * 3 + 2];
      const float* rwp = rw + m * 90 + r * 9;
#pragma unroll
      for (int d = 0; d < 3; d++)
        p[r][d] = x0 * rwp[d] + x1 * rwp[3 + d] + x2 * rwp[6 + d];
    }
    float lg[10];
#pragma unroll
    for (int r = 0; r < 10; r++) lg[r] = 0.f;
    float v0 = 0.f, v1 = 0.f, v2 = 0.f;
    for (int it = 0; it < 3; ++it){
      float lr[10]; float mx = -3.0e38f;
#pragma unroll
      for (int r = 0; r < 10; r++){ lr[r] = (r <= tt) ? lg[r] : NEG_; mx = fmaxf(mx, lr[r]); }
      float e[10]; float sum = 0.f;
#pragma unroll
      for (int r = 0; r < 10; r++){ e[r] = expf(lr[r] - mx); sum += e[r]; }
      const float inv = 1.f / sum;
      v0 = 0.f; v1 = 0.f; v2 = 0.f;
#pragma unroll
      for (int r = 0; r < 10; r++){
        const float pr = e[r] * inv;
        v0 += pr * p[r][0]; v1 += pr * p[r][1]; v2 += pr * p[r][2];
      }
      if (it < 2){
        float sq = v0 * v0 + v1 * v1 + v2 * v2 + 1e-16f;
        float scale = (sq / (1.f + sq)) / sqrtf(sq);
        const float o0 = v0 * scale, o1 = v1 * scale, o2 = v2 * scale;
#pragma unroll
        for (int r = 0; r < 10; r++) lg[r] += p[r][0] * o0 + p[r][1] * o1 + p[r][2] * o2;
      }
    }
    float* dst = voteflat + (size_t)m * 49152 + (size_t)(n0 + r2) * 3;
    dst[0] = v0; dst[1] = v1; dst[2] = v2;
  }
}

// ---------------- h_pre = x + (h_caps @ larger_w^T + b) * glarger  -> bf16 ----------------
__global__ __launch_bounds__(256) void hpre_kernel(
    const float* __restrict__ x, const float* __restrict__ voteflat,
    const float* __restrict__ larger_w, const float* __restrict__ larger_b,
    const float* __restrict__ glarger, u16* __restrict__ hpre)
{
  size_t idx = (size_t)blockIdx.x * 256 + threadIdx.x;
  if (idx >= (size_t)16384 * 768) return;
  int h = (int)(idx % 768);
  size_t n = idx / 768;
  const float* vc = voteflat + n * 9;   // flat reinterpretation of [M,N,C] -> [N', 9]
  const float* lw = larger_w + (size_t)h * 9;
  float acc = larger_b[h];
#pragma unroll
  for (int j = 0; j < 9; j++) acc += vc[j] * lw[j];
  float hp = x[idx] + acc * glarger[h];
  hpre[idx] = f2bf(hp);
}

// ---------------- bf16 MFMA GEMM, C = A(MxK) * B(NxK)^T, fused gelu*gate epilogue ----------
// MODE 0: store bf16(gelu(acc+bias)*gate)          (GEMM1 -> Hm)
// MODE 1: store f32 x + gelu(acc+bias)*gate        (GEMM2 -> out)
template<int MODE>
__global__ __launch_bounds__(256) void gemm_bt(
    const u16* __restrict__ A, const u16* __restrict__ B,
    const float* __restrict__ bias, const float* __restrict__ gate,
    const float* __restrict__ xres, void* __restrict__ Cout,
    int M, int N, int K, int NT_N)
{
  __shared__ __align__(16) u16 As[128 * 64];
  __shared__ __align__(16) u16 Bs[128 * 64];
  const int bid = blockIdx.x;
  const int bm = bid / NT_N, bn = bid % NT_N;
  const int m0 = bm * 128, n0 = bn * 128;
  const int tid = threadIdx.x;
  const int w = tid >> 6, l = tid & 63;
  const int wm = w >> 1, wn = w & 1;
  const int lrow = l >> 3;
  const int lcol = (l & 7) * 8;

  f32x4 acc[4][4];
#pragma unroll
  for (int i = 0; i < 4; i++)
#pragma unroll
    for (int j = 0; j < 4; j++)
      acc[i][j] = (f32x4){0.f, 0.f, 0.f, 0.f};

  for (int k0 = 0; k0 < K; k0 += 64){
#pragma unroll
    for (int i = 0; i < 4; i++){
      const u16* ag = A + (size_t)(m0 + i * 32 + w * 8 + lrow) * K + (k0 + lcol);
      async_load16(ag, (void*)&As[(i * 32 + w * 8) * 64]);
    }
#pragma unroll
    for (int i = 0; i < 4; i++){
      const u16* bg = B + (size_t)(n0 + i * 32 + w * 8 + lrow) * K + (k0 + lcol);
      async_load16(bg, (void*)&Bs[(i * 32 + w * 8) * 64]);
    }
    __syncthreads();
#pragma unroll
    for (int ks = 0; ks < 2; ks++){
      bf16x8 af[4], bf2[4];
#pragma unroll
      for (int fm = 0; fm < 4; fm++)
        af[fm] = *(const bf16x8*)&As[(wm * 64 + fm * 16 + (l & 15)) * 64 + ks * 32 + (l >> 4) * 8];
#pragma unroll
      for (int fn = 0; fn < 4; fn++)
        bf2[fn] = *(const bf16x8*)&Bs[(wn * 64 + fn * 16 + (l & 15)) * 64 + ks * 32 + (l >> 4) * 8];
#pragma unroll
      for (int fm = 0; fm < 4; fm++)
#pragma unroll
        for (int fn = 0; fn < 4; fn++)
          acc[fm][fn] = __builtin_amdgcn_mfma_f32_16x16x32_bf16(af[fm], bf2[fn], acc[fm][fn], 0, 0, 0);
    }
    __syncthreads();
  }

#pragma unroll
  for (int fm = 0; fm < 4; fm++){
    const int rbase = m0 + wm * 64 + fm * 16 + ((l >> 4) << 2);
#pragma unroll
    for (int fn = 0; fn < 4; fn++){
      const int col = n0 + wn * 64 + fn * 16 + (l & 15);
      const float bv = bias[col], gv = gate[col];
#pragma unroll
      for (int j = 0; j < 4; j++){
        const int rowg = rbase + j;
        float v = acc[fm][fn][j] + bv;
        float g = gelu_exact(v) * gv;
        if (MODE == 0){
          ((u16*)Cout)[(size_t)rowg * N + col] = f2bf(g);
        } else {
          size_t o = (size_t)rowg * N + col;
          ((float*)Cout)[o] = xres[o] + g;
        }
      }
    }
  }
}

// ---------------- launcher ----------------
extern "C" void kernel_launch(void* const* d_in, const int* in_sizes, int n_in,
                              void* d_out, int out_size, void* d_ws, size_t ws_size,
                              hipStream_t stream)
{
  const float* x       = (const float*)d_in[0];
  const int*   t       = (const int*)  d_in[1];
  const float* s       = (const float*)d_in[2];
  const float* fc1_w   = (const float*)d_in[3];
  const float* fc1_b   = (const float*)d_in[4];
  const float* fc2_w   = (const float*)d_in[5];
  const float* fc2_b   = (const float*)d_in[6];
  const float* efc1    = (const float*)d_in[7];
  const float* efc2    = (const float*)d_in[8];
  const float* sem_w   = (const float*)d_in[9];
  const float* sem_b   = (const float*)d_in[10];
  const float* rw      = (const float*)d_in[11];
  const float* larger_w= (const float*)d_in[12];
  const float* larger_b= (const float*)d_in[13];
  const float* elarger = (const float*)d_in[14];

  char* ws = (char*)d_ws;
  float* vote    = (float*)(ws + 0);         //  589824 B  [3][16384][3] f32
  float* gfc1p   = (float*)(ws + 589824);    //    8192 B  [2048]
  float* b1p     = (float*)(ws + 598016);    //    8192 B  [2048]
  float* gfc2    = (float*)(ws + 606208);    //    3072 B  [768]
  float* glarger = (float*)(ws + 609280);    //    3072 B  [768]
  u16*   Bw1     = (u16*)  (ws + 612352);    // 3145728 B  [2048][768] bf16
  u16*   Bw2     = (u16*)  (ws + 3758080);   // 3145728 B  [768][2048] bf16
  u16*   hpre    = (u16*)  (ws + 6903808);   // 25165824 B [16384][768] bf16
  u16*   Hm      = (u16*)  (ws + 32069632);  // 67108864 B [16384][2048] bf16
  // total 99,178,496 B

  prep_gates<<<8, 256, 0, stream>>>(s, t, efc1, efc2, elarger, fc1_b, gfc1p, b1p, gfc2, glarger);
  conv_w1<<<6144, 256, 0, stream>>>(fc1_w, Bw1);
  conv_w2<<<6144, 256, 0, stream>>>(fc2_w, Bw2);
  sem_route<<<2048, 256, 0, stream>>>(x, t, sem_w, sem_b, rw, vote);
  hpre_kernel<<<49152, 256, 0, stream>>>(x, vote, larger_w, larger_b, glarger, hpre);
  gemm_bt<0><<<2048, 256, 0, stream>>>(hpre, Bw1, b1p, gfc1p, nullptr, (void*)Hm,
                                       16384, 2048, 768, 16);
  gemm_bt<1><<<768, 256, 0, stream>>>(Hm, Bw2, fc2_b, gfc2, x, d_out,
                                      16384, 768, 2048, 6);
}

// Round 2
// 350.266 us; speedup vs baseline: 1.3682x; 1.3682x over previous
//
#include <hip/hip_runtime.h>
#include <stdint.h>
#include <math.h>

typedef unsigned short u16;
typedef __bf16 bf16x8 __attribute__((ext_vector_type(8)));
typedef float f32x4 __attribute__((ext_vector_type(4)));

#define NEG_ -10000.0f

__device__ __forceinline__ u16 f2bf(float f){
  unsigned u = __float_as_uint(f);
  unsigned r = (u + 0x7fffu + ((u >> 16) & 1u)) >> 16;
  return (u16)r;
}

__device__ __forceinline__ float gelu_exact(float v){
  return 0.5f * v * (1.f + erff(v * 0.70710678118654752f));
}
__device__ __forceinline__ float sigmoidf_(float z){ return 1.f / (1.f + expf(-z)); }

__device__ __forceinline__ void async_load16(const void* g, void* lds){
  typedef const __attribute__((address_space(1))) unsigned int* gp_t;
  typedef __attribute__((address_space(3))) unsigned int* lp_t;
  __builtin_amdgcn_global_load_lds((gp_t)(uintptr_t)g, (lp_t)(uintptr_t)lds, 16, 0, 0);
}

// ---------------- gates + padded bias ----------------
__global__ __launch_bounds__(256) void prep_gates(
    const float* __restrict__ s, const int* __restrict__ t,
    const float* __restrict__ efc1, const float* __restrict__ efc2,
    const float* __restrict__ elarger, const float* __restrict__ fc1_b,
    float* __restrict__ gfc1p, float* __restrict__ b1p,
    float* __restrict__ gfc2, float* __restrict__ glarger)
{
  int i = blockIdx.x * 256 + threadIdx.x;
  float sv = s[0]; int tt = t[0];
  if (i < 2048){
    float g = 0.f, b = 0.f;
    if (i < 2000){ g = sigmoidf_(sv * efc1[tt * 2000 + i]); b = fc1_b[i]; }
    gfc1p[i] = g; b1p[i] = b;
  }
  if (i < 768){
    gfc2[i]    = sigmoidf_(sv * efc2[tt * 768 + i]);
    glarger[i] = sigmoidf_(sv * elarger[tt * 768 + i]);
  }
}

// ---------------- weight conversions (zero-padded) ----------------
__global__ __launch_bounds__(256) void conv_w1(const float* __restrict__ fc1_w, u16* __restrict__ Bw1){
  int idx = blockIdx.x * 256 + threadIdx.x;            // [2048][768]
  if (idx >= 2048 * 768) return;
  int n = idx / 768, k = idx % 768;
  float v = (n < 2000) ? fc1_w[n * 768 + k] : 0.f;
  Bw1[idx] = f2bf(v);
}
__global__ __launch_bounds__(256) void conv_w2(const float* __restrict__ fc2_w, u16* __restrict__ Bw2){
  int idx = blockIdx.x * 256 + threadIdx.x;            // [768][2048]
  if (idx >= 768 * 2048) return;
  int h = idx / 2048, k = idx % 2048;
  float v = (k < 2000) ? fc2_w[h * 2000 + k] : 0.f;
  Bw2[idx] = f2bf(v);
}

// ---------------- sem capsules + squash + priors + dynamic routing (wave-parallel) ----
// 1 wave = 4 tokens. x rows in registers; each capsule dot = whole-wave FMA +
// 6-step shfl_xor butterfly (4 tokens reduced simultaneously). Squash+routing by
// 12 lanes/wave via tiny LDS. Votes stored m-major [3][16384][3].
__global__ __launch_bounds__(256) void sem_route(
    const float* __restrict__ x, const int* __restrict__ t_ptr,
    const float* __restrict__ sem_w, const float* __restrict__ sem_b,
    const float* __restrict__ rw, float* __restrict__ voteflat)
{
  __shared__ float semv[4][4][32];   // [wave][token][cap 30(pad32)], flat order c*10+t
  const int tid  = threadIdx.x;
  const int wid  = tid >> 6, lane = tid & 63;
  const int tok0 = (blockIdx.x * 4 + wid) * 4;

  // x rows for 4 tokens: lane holds floats [lane*4 + 256*j .. +3], j=0..2
  float4 xr[4][3];
#pragma unroll
  for (int tk = 0; tk < 4; tk++)
#pragma unroll
    for (int j = 0; j < 3; j++)
      xr[tk][j] = *(const float4*)(x + (size_t)(tok0 + tk) * 768 + j * 256 + lane * 4);

  // 30 capsule dot products
  for (int cap = 0; cap < 30; ++cap){
    const int c = cap / 10, tt2 = cap % 10;
    const float* wrow = sem_w + (size_t)(tt2 * 3 + c) * 768;
    const float4 w0 = *(const float4*)(wrow +       lane * 4);
    const float4 w1 = *(const float4*)(wrow + 256 + lane * 4);
    const float4 w2 = *(const float4*)(wrow + 512 + lane * 4);
    float d[4];
#pragma unroll
    for (int tk = 0; tk < 4; tk++){
      const float4 a0 = xr[tk][0], a1 = xr[tk][1], a2 = xr[tk][2];
      d[tk] = a0.x * w0.x + a0.y * w0.y + a0.z * w0.z + a0.w * w0.w
            + a1.x * w1.x + a1.y * w1.y + a1.z * w1.z + a1.w * w1.w
            + a2.x * w2.x + a2.y * w2.y + a2.z * w2.z + a2.w * w2.w;
    }
#pragma unroll
    for (int m = 1; m < 64; m <<= 1){
#pragma unroll
      for (int tk = 0; tk < 4; tk++) d[tk] += __shfl_xor(d[tk], m, 64);
    }
    if (lane < 4) semv[wid][lane][cap] = d[lane] + sem_b[tt2 * 3 + c];
  }
  __syncthreads();

  // squash over t within each (token, c) group of 10
  if (lane < 12){
    const int tk = lane / 3, c = lane % 3;
    float v[10]; float sq = 0.f;
#pragma unroll
    for (int j = 0; j < 10; j++){ v[j] = semv[wid][tk][c * 10 + j]; sq += v[j] * v[j]; }
    sq += 1e-16f;
    const float scale = (sq / (1.f + sq)) / sqrtf(sq);
#pragma unroll
    for (int j = 0; j < 10; j++) semv[wid][tk][c * 10 + j] = v[j] * scale;
  }
  __syncthreads();

  // dynamic routing per (token, m)
  if (lane < 12){
    const int tk = lane / 3, m = lane % 3;
    const int tt = t_ptr[0];
    float p[10][3];
#pragma unroll
    for (int r = 0; r < 10; r++){
      const float x0 = semv[wid][tk][r * 3 + 0];
      const float x1 = semv[wid][tk][r * 3 + 1];
      const float x2 = semv[wid][tk][r * 3 + 2];
      const float* rwp = rw + m * 90 + r * 9;
#pragma unroll
      for (int d = 0; d < 3; d++)
        p[r][d] = x0 * rwp[d] + x1 * rwp[3 + d] + x2 * rwp[6 + d];
    }
    float lg[10];
#pragma unroll
    for (int r = 0; r < 10; r++) lg[r] = 0.f;
    float v0 = 0.f, v1 = 0.f, v2 = 0.f;
    for (int it = 0; it < 3; ++it){
      float lr[10]; float mx = -3.0e38f;
#pragma unroll
      for (int r = 0; r < 10; r++){ lr[r] = (r <= tt) ? lg[r] : NEG_; mx = fmaxf(mx, lr[r]); }
      float e[10]; float sum = 0.f;
#pragma unroll
      for (int r = 0; r < 10; r++){ e[r] = expf(lr[r] - mx); sum += e[r]; }
      const float inv = 1.f / sum;
      v0 = 0.f; v1 = 0.f; v2 = 0.f;
#pragma unroll
      for (int r = 0; r < 10; r++){
        const float pr = e[r] * inv;
        v0 += pr * p[r][0]; v1 += pr * p[r][1]; v2 += pr * p[r][2];
      }
      if (it < 2){
        float sq = v0 * v0 + v1 * v1 + v2 * v2 + 1e-16f;
        float scale = (sq / (1.f + sq)) / sqrtf(sq);
        const float o0 = v0 * scale, o1 = v1 * scale, o2 = v2 * scale;
#pragma unroll
        for (int r = 0; r < 10; r++) lg[r] += p[r][0] * o0 + p[r][1] * o1 + p[r][2] * o2;
      }
    }
    float* dst = voteflat + (size_t)m * 49152 + (size_t)(tok0 + tk) * 3;
    dst[0] = v0; dst[1] = v1; dst[2] = v2;
  }
}

// ---------------- h_pre = x + (h_caps @ larger_w^T + b) * glarger  -> bf16 ----------------
__global__ __launch_bounds__(256) void hpre_kernel(
    const float* __restrict__ x, const float* __restrict__ voteflat,
    const float* __restrict__ larger_w, const float* __restrict__ larger_b,
    const float* __restrict__ glarger, u16* __restrict__ hpre)
{
  size_t idx = (size_t)blockIdx.x * 256 + threadIdx.x;
  if (idx >= (size_t)16384 * 768) return;
  int h = (int)(idx % 768);
  size_t n = idx / 768;
  const float* vc = voteflat + n * 9;   // flat view: [M,N,C] m-major -> [N', 9]? (note: m-major over N)
  // voteflat is [3][16384][3]; h_caps[n][j] with j=m*3+c maps to voteflat[m][n][c]
  const float* lw = larger_w + (size_t)h * 9;
  float acc = larger_b[h];
#pragma unroll
  for (int m = 0; m < 3; m++)
#pragma unroll
    for (int c = 0; c < 3; c++)
      acc += voteflat[(size_t)m * 49152 + n * 3 + c] * lw[m * 3 + c];
  (void)vc;
  float hp = x[idx] + acc * glarger[h];
  hpre[idx] = f2bf(hp);
}

// ---------------- bf16 MFMA GEMM, C = A(MxK) * B(NxK)^T, fused gelu*gate epilogue ----------
// MODE 0: store bf16(gelu(acc+bias)*gate)          (GEMM1 -> Hm)
// MODE 1: store f32 x + gelu(acc+bias)*gate        (GEMM2 -> out)
template<int MODE>
__global__ __launch_bounds__(256) void gemm_bt(
    const u16* __restrict__ A, const u16* __restrict__ B,
    const float* __restrict__ bias, const float* __restrict__ gate,
    const float* __restrict__ xres, void* __restrict__ Cout,
    int M, int N, int K, int NT_N)
{
  __shared__ __align__(16) u16 As[128 * 64];
  __shared__ __align__(16) u16 Bs[128 * 64];
  const int bid = blockIdx.x;
  const int bm = bid / NT_N, bn = bid % NT_N;
  const int m0 = bm * 128, n0 = bn * 128;
  const int tid = threadIdx.x;
  const int w = tid >> 6, l = tid & 63;
  const int wm = w >> 1, wn = w & 1;
  const int lrow = l >> 3;
  const int lcol = (l & 7) * 8;

  f32x4 acc[4][4];
#pragma unroll
  for (int i = 0; i < 4; i++)
#pragma unroll
    for (int j = 0; j < 4; j++)
      acc[i][j] = (f32x4){0.f, 0.f, 0.f, 0.f};

  for (int k0 = 0; k0 < K; k0 += 64){
#pragma unroll
    for (int i = 0; i < 4; i++){
      const u16* ag = A + (size_t)(m0 + i * 32 + w * 8 + lrow) * K + (k0 + lcol);
      async_load16(ag, (void*)&As[(i * 32 + w * 8) * 64]);
    }
#pragma unroll
    for (int i = 0; i < 4; i++){
      const u16* bg = B + (size_t)(n0 + i * 32 + w * 8 + lrow) * K + (k0 + lcol);
      async_load16(bg, (void*)&Bs[(i * 32 + w * 8) * 64]);
    }
    __syncthreads();
#pragma unroll
    for (int ks = 0; ks < 2; ks++){
      bf16x8 af[4], bf2[4];
#pragma unroll
      for (int fm = 0; fm < 4; fm++)
        af[fm] = *(const bf16x8*)&As[(wm * 64 + fm * 16 + (l & 15)) * 64 + ks * 32 + (l >> 4) * 8];
#pragma unroll
      for (int fn = 0; fn < 4; fn++)
        bf2[fn] = *(const bf16x8*)&Bs[(wn * 64 + fn * 16 + (l & 15)) * 64 + ks * 32 + (l >> 4) * 8];
#pragma unroll
      for (int fm = 0; fm < 4; fm++)
#pragma unroll
        for (int fn = 0; fn < 4; fn++)
          acc[fm][fn] = __builtin_amdgcn_mfma_f32_16x16x32_bf16(af[fm], bf2[fn], acc[fm][fn], 0, 0, 0);
    }
    __syncthreads();
  }

#pragma unroll
  for (int fm = 0; fm < 4; fm++){
    const int rbase = m0 + wm * 64 + fm * 16 + ((l >> 4) << 2);
#pragma unroll
    for (int fn = 0; fn < 4; fn++){
      const int col = n0 + wn * 64 + fn * 16 + (l & 15);
      const float bv = bias[col], gv = gate[col];
#pragma unroll
      for (int j = 0; j < 4; j++){
        const int rowg = rbase + j;
        float v = acc[fm][fn][j] + bv;
        float g = gelu_exact(v) * gv;
        if (MODE == 0){
          ((u16*)Cout)[(size_t)rowg * N + col] = f2bf(g);
        } else {
          size_t o = (size_t)rowg * N + col;
          ((float*)Cout)[o] = xres[o] + g;
        }
      }
    }
  }
}

// ---------------- launcher ----------------
extern "C" void kernel_launch(void* const* d_in, const int* in_sizes, int n_in,
                              void* d_out, int out_size, void* d_ws, size_t ws_size,
                              hipStream_t stream)
{
  const float* x       = (const float*)d_in[0];
  const int*   t       = (const int*)  d_in[1];
  const float* s       = (const float*)d_in[2];
  const float* fc1_w   = (const float*)d_in[3];
  const float* fc1_b   = (const float*)d_in[4];
  const float* fc2_w   = (const float*)d_in[5];
  const float* fc2_b   = (const float*)d_in[6];
  const float* efc1    = (const float*)d_in[7];
  const float* efc2    = (const float*)d_in[8];
  const float* sem_w   = (const float*)d_in[9];
  const float* sem_b   = (const float*)d_in[10];
  const float* rw      = (const float*)d_in[11];
  const float* larger_w= (const float*)d_in[12];
  const float* larger_b= (const float*)d_in[13];
  const float* elarger = (const float*)d_in[14];

  char* ws = (char*)d_ws;
  float* vote    = (float*)(ws + 0);         //  589824 B  [3][16384][3] f32
  float* gfc1p   = (float*)(ws + 589824);    //    8192 B  [2048]
  float* b1p     = (float*)(ws + 598016);    //    8192 B  [2048]
  float* gfc2    = (float*)(ws + 606208);    //    3072 B  [768]
  float* glarger = (float*)(ws + 609280);    //    3072 B  [768]
  u16*   Bw1     = (u16*)  (ws + 612352);    // 3145728 B  [2048][768] bf16
  u16*   Bw2     = (u16*)  (ws + 3758080);   // 3145728 B  [768][2048] bf16
  u16*   hpre    = (u16*)  (ws + 6903808);   // 25165824 B [16384][768] bf16
  u16*   Hm      = (u16*)  (ws + 32069632);  // 67108864 B [16384][2048] bf16
  // total 99,178,496 B

  prep_gates<<<8, 256, 0, stream>>>(s, t, efc1, efc2, elarger, fc1_b, gfc1p, b1p, gfc2, glarger);
  conv_w1<<<6144, 256, 0, stream>>>(fc1_w, Bw1);
  conv_w2<<<6144, 256, 0, stream>>>(fc2_w, Bw2);
  sem_route<<<1024, 256, 0, stream>>>(x, t, sem_w, sem_b, rw, vote);
  hpre_kernel<<<49152, 256, 0, stream>>>(x, vote, larger_w, larger_b, glarger, hpre);
  gemm_bt<0><<<2048, 256, 0, stream>>>(hpre, Bw1, b1p, gfc1p, nullptr, (void*)Hm,
                                       16384, 2048, 768, 16);
  gemm_bt<1><<<768, 256, 0, stream>>>(Hm, Bw2, fc2_b, gfc2, x, d_out,
                                      16384, 768, 2048, 6);
}

// Round 3
// 287.203 us; speedup vs baseline: 1.6686x; 1.2196x over previous
//
#include <hip/hip_runtime.h>
#include <stdint.h>
#include <math.h>

typedef unsigned short u16;
typedef __bf16 bf16x8 __attribute__((ext_vector_type(8)));
typedef float f32x4 __attribute__((ext_vector_type(4)));

#define NEG_ -10000.0f

__device__ __forceinline__ u16 f2bf(float f){
  unsigned u = __float_as_uint(f);
  unsigned r = (u + 0x7fffu + ((u >> 16) & 1u)) >> 16;
  return (u16)r;
}

__device__ __forceinline__ float gelu_exact(float v){
  return 0.5f * v * (1.f + erff(v * 0.70710678118654752f));
}
__device__ __forceinline__ float sigmoidf_(float z){ return 1.f / (1.f + expf(-z)); }

__device__ __forceinline__ void async_load16(const void* g, void* lds){
  typedef const __attribute__((address_space(1))) unsigned int* gp_t;
  typedef __attribute__((address_space(3))) unsigned int* lp_t;
  __builtin_amdgcn_global_load_lds((gp_t)(uintptr_t)g, (lp_t)(uintptr_t)lds, 16, 0, 0);
}

__device__ __forceinline__ unsigned swz(unsigned o){ return o ^ ((o >> 3) & 0x70u); }

// ---------------- gates + padded bias ----------------
__global__ __launch_bounds__(256) void prep_gates(
    const float* __restrict__ s, const int* __restrict__ t,
    const float* __restrict__ efc1, const float* __restrict__ efc2,
    const float* __restrict__ elarger, const float* __restrict__ fc1_b,
    float* __restrict__ gfc1p, float* __restrict__ b1p,
    float* __restrict__ gfc2, float* __restrict__ glarger)
{
  int i = blockIdx.x * 256 + threadIdx.x;
  float sv = s[0]; int tt = t[0];
  if (i < 2048){
    float g = 0.f, b = 0.f;
    if (i < 2000){ g = sigmoidf_(sv * efc1[tt * 2000 + i]); b = fc1_b[i]; }
    gfc1p[i] = g; b1p[i] = b;
  }
  if (i < 768){
    gfc2[i]    = sigmoidf_(sv * efc2[tt * 768 + i]);
    glarger[i] = sigmoidf_(sv * elarger[tt * 768 + i]);
  }
}

// ---------------- weight conversions (zero-padded) ----------------
__global__ __launch_bounds__(256) void conv_w1(const float* __restrict__ fc1_w, u16* __restrict__ Bw1){
  int idx = blockIdx.x * 256 + threadIdx.x;            // [2048][768]
  if (idx >= 2048 * 768) return;
  int n = idx / 768, k = idx % 768;
  float v = (n < 2000) ? fc1_w[n * 768 + k] : 0.f;
  Bw1[idx] = f2bf(v);
}
__global__ __launch_bounds__(256) void conv_w2(const float* __restrict__ fc2_w, u16* __restrict__ Bw2){
  int idx = blockIdx.x * 256 + threadIdx.x;            // [768][2048]
  if (idx >= 768 * 2048) return;
  int h = idx / 2048, k = idx % 2048;
  float v = (k < 2000) ? fc2_w[h * 2000 + k] : 0.f;
  Bw2[idx] = f2bf(v);
}

// ---------------- sem capsules + squash + priors + dynamic routing (wave-parallel) ----
__global__ __launch_bounds__(256) void sem_route(
    const float* __restrict__ x, const int* __restrict__ t_ptr,
    const float* __restrict__ sem_w, const float* __restrict__ sem_b,
    const float* __restrict__ rw, float* __restrict__ voteflat)
{
  __shared__ float semv[4][4][32];
  const int tid  = threadIdx.x;
  const int wid  = tid >> 6, lane = tid & 63;
  const int tok0 = (blockIdx.x * 4 + wid) * 4;

  float4 xr[4][3];
#pragma unroll
  for (int tk = 0; tk < 4; tk++)
#pragma unroll
    for (int j = 0; j < 3; j++)
      xr[tk][j] = *(const float4*)(x + (size_t)(tok0 + tk) * 768 + j * 256 + lane * 4);

  for (int cap = 0; cap < 30; ++cap){
    const int c = cap / 10, tt2 = cap % 10;
    const float* wrow = sem_w + (size_t)(tt2 * 3 + c) * 768;
    const float4 w0 = *(const float4*)(wrow +       lane * 4);
    const float4 w1 = *(const float4*)(wrow + 256 + lane * 4);
    const float4 w2 = *(const float4*)(wrow + 512 + lane * 4);
    float d[4];
#pragma unroll
    for (int tk = 0; tk < 4; tk++){
      const float4 a0 = xr[tk][0], a1 = xr[tk][1], a2 = xr[tk][2];
      d[tk] = a0.x * w0.x + a0.y * w0.y + a0.z * w0.z + a0.w * w0.w
            + a1.x * w1.x + a1.y * w1.y + a1.z * w1.z + a1.w * w1.w
            + a2.x * w2.x + a2.y * w2.y + a2.z * w2.z + a2.w * w2.w;
    }
#pragma unroll
    for (int m = 1; m < 64; m <<= 1){
#pragma unroll
      for (int tk = 0; tk < 4; tk++) d[tk] += __shfl_xor(d[tk], m, 64);
    }
    if (lane < 4) semv[wid][lane][cap] = d[lane] + sem_b[tt2 * 3 + c];
  }
  __syncthreads();

  if (lane < 12){
    const int tk = lane / 3, c = lane % 3;
    float v[10]; float sq = 0.f;
#pragma unroll
    for (int j = 0; j < 10; j++){ v[j] = semv[wid][tk][c * 10 + j]; sq += v[j] * v[j]; }
    sq += 1e-16f;
    const float scale = (sq / (1.f + sq)) / sqrtf(sq);
#pragma unroll
    for (int j = 0; j < 10; j++) semv[wid][tk][c * 10 + j] = v[j] * scale;
  }
  __syncthreads();

  if (lane < 12){
    const int tk = lane / 3, m = lane % 3;
    const int tt = t_ptr[0];
    float p[10][3];
#pragma unroll
    for (int r = 0; r < 10; r++){
      const float x0 = semv[wid][tk][r * 3 + 0];
      const float x1 = semv[wid][tk][r * 3 + 1];
      const float x2 = semv[wid][tk][r * 3 + 2];
      const float* rwp = rw + m * 90 + r * 9;
#pragma unroll
      for (int d = 0; d < 3; d++)
        p[r][d] = x0 * rwp[d] + x1 * rwp[3 + d] + x2 * rwp[6 + d];
    }
    float lg[10];
#pragma unroll
    for (int r = 0; r < 10; r++) lg[r] = 0.f;
    float v0 = 0.f, v1 = 0.f, v2 = 0.f;
    for (int it = 0; it < 3; ++it){
      float lr[10]; float mx = -3.0e38f;
#pragma unroll
      for (int r = 0; r < 10; r++){ lr[r] = (r <= tt) ? lg[r] : NEG_; mx = fmaxf(mx, lr[r]); }
      float e[10]; float sum = 0.f;
#pragma unroll
      for (int r = 0; r < 10; r++){ e[r] = expf(lr[r] - mx); sum += e[r]; }
      const float inv = 1.f / sum;
      v0 = 0.f; v1 = 0.f; v2 = 0.f;
#pragma unroll
      for (int r = 0; r < 10; r++){
        const float pr = e[r] * inv;
        v0 += pr * p[r][0]; v1 += pr * p[r][1]; v2 += pr * p[r][2];
      }
      if (it < 2){
        float sq = v0 * v0 + v1 * v1 + v2 * v2 + 1e-16f;
        float scale = (sq / (1.f + sq)) / sqrtf(sq);
        const float o0 = v0 * scale, o1 = v1 * scale, o2 = v2 * scale;
#pragma unroll
        for (int r = 0; r < 10; r++) lg[r] += p[r][0] * o0 + p[r][1] * o1 + p[r][2] * o2;
      }
    }
    float* dst = voteflat + (size_t)m * 49152 + (size_t)(tok0 + tk) * 3;
    dst[0] = v0; dst[1] = v1; dst[2] = v2;
  }
}

// ---------------- h_pre = x + (h_caps @ larger_w^T + b) * glarger  -> bf16 ----------------
__global__ __launch_bounds__(256) void hpre_kernel(
    const float* __restrict__ x, const float* __restrict__ voteflat,
    const float* __restrict__ larger_w, const float* __restrict__ larger_b,
    const float* __restrict__ glarger, u16* __restrict__ hpre)
{
  size_t idx = (size_t)blockIdx.x * 256 + threadIdx.x;
  if (idx >= (size_t)16384 * 768) return;
  int h = (int)(idx % 768);
  size_t n = idx / 768;
  const float* lw = larger_w + (size_t)h * 9;
  float acc = larger_b[h];
#pragma unroll
  for (int m = 0; m < 3; m++)
#pragma unroll
    for (int c = 0; c < 3; c++)
      acc += voteflat[(size_t)m * 49152 + n * 3 + c] * lw[m * 3 + c];
  float hp = x[idx] + acc * glarger[h];
  hpre[idx] = f2bf(hp);
}

// ---------------- 256x256 8-phase bf16 MFMA GEMM, C = A(MxK) * B(NxK)^T ----------------
// T1 XCD swizzle + T2 LDS XOR swizzle + T3/T4 phased counted-vmcnt pipeline + T5 setprio.
// MODE 0: store bf16(gelu(acc+bias)*gate);  MODE 1: store f32 xres + gelu(acc+bias)*gate.
template<int MODE, int NDIM, int KDIM>
__global__ __launch_bounds__(512, 2) void gemm8(
    const u16* __restrict__ A, const u16* __restrict__ B,
    const float* __restrict__ bias, const float* __restrict__ gate,
    const float* __restrict__ xres, void* __restrict__ Cout, int NT_N)
{
  __shared__ __align__(16) u16 As[2][16384];   // [buf][2 halves of 128 rows x 64 k]
  __shared__ __align__(16) u16 Bs[2][16384];
  constexpr int NT = KDIM / 64;
  constexpr int NITER = NT / 2;

  const int nwg = (int)gridDim.x;              // multiple of 8
  const int cpx = nwg >> 3;
  const int wg  = ((int)blockIdx.x & 7) * cpx + ((int)blockIdx.x >> 3);
  const int bm = wg / NT_N, bn = wg % NT_N;
  const int m0 = bm * 256, n0 = bn * 256;
  const int tid = (int)threadIdx.x;
  const int w = tid >> 6, l = tid & 63;
  const int wr = w >> 2, wc = w & 3;           // 2 x 4 wave grid; wave tile 128 x 64

  f32x4 acc[8][4];
#pragma unroll
  for (int i = 0; i < 8; i++)
#pragma unroll
    for (int j = 0; j < 4; j++)
      acc[i][j] = (f32x4){0.f, 0.f, 0.f, 0.f};

  bf16x8 bfr[4][2];

  // stage one 256x64 tile: linear LDS dest, inverse(=same)-swizzled global source (rule #21)
  auto stage = [&](const u16* __restrict__ src, int r0, int k0, u16* lds){
#pragma unroll
    for (int j = 0; j < 4; ++j){
      const int half = j >> 1, jj = j & 1;
      unsigned o  = (unsigned)(jj * 8192 + tid * 16);   // within-half byte offset (linear)
      unsigned lo = swz(o);                             // logical element position
      int row  = half * 128 + (int)(lo >> 7);
      int colb = (int)(lo & 127u);
      const u16* g = src + (size_t)(r0 + row) * KDIM + (k0 + (colb >> 1));
      char* d = (char*)lds + half * 16384 + jj * 8192 + w * 1024;  // wave-uniform base
      async_load16(g, d);
    }
  };

  auto compute_tile = [&](int cur){
    const char* abase = (const char*)As[cur] + wr * 16384;
    const char* bbase = (const char*)Bs[cur] + (wc >> 1) * 16384;
#pragma unroll
    for (int q = 0; q < 4; ++q){
      if (q == 0){
#pragma unroll
        for (int g = 0; g < 4; ++g)
#pragma unroll
          for (int ks = 0; ks < 2; ++ks){
            unsigned o = (unsigned)((((wc & 1) * 64 + g * 16 + (l & 15)) << 7) + ks * 64 + ((l >> 4) << 4));
            bfr[g][ks] = *(const bf16x8*)(bbase + swz(o));
          }
      }
      bf16x8 afr[2][2];
#pragma unroll
      for (int fi = 0; fi < 2; ++fi)
#pragma unroll
        for (int ks = 0; ks < 2; ++ks){
          unsigned o = (unsigned)((((2 * q + fi) * 16 + (l & 15)) << 7) + ks * 64 + ((l >> 4) << 4));
          afr[fi][ks] = *(const bf16x8*)(abase + swz(o));
        }
      asm volatile("" ::: "memory");
      __builtin_amdgcn_s_barrier();
      asm volatile("" ::: "memory");
      __builtin_amdgcn_s_setprio(1);
#pragma unroll
      for (int fi = 0; fi < 2; ++fi)
#pragma unroll
        for (int g = 0; g < 4; ++g)
#pragma unroll
          for (int ks = 0; ks < 2; ++ks)
            acc[2 * q + fi][g] = __builtin_amdgcn_mfma_f32_16x16x32_bf16(
                afr[fi][ks], bfr[g][ks], acc[2 * q + fi][g], 0, 0, 0);
      __builtin_amdgcn_s_setprio(0);
      asm volatile("" ::: "memory");
      __builtin_amdgcn_s_barrier();
      asm volatile("" ::: "memory");
    }
  };

  // prologue: tile0 -> buf0, tile1 -> buf1; wait tile0 (8 of tile1 left in flight)
  stage(A, m0, 0, As[0]);  stage(B, n0, 0, Bs[0]);
  stage(A, m0, 64, As[1]); stage(B, n0, 64, Bs[1]);
  asm volatile("s_waitcnt vmcnt(8)" ::: "memory");
  __builtin_amdgcn_s_barrier();
  asm volatile("" ::: "memory");

  for (int i = 0; i < NITER - 1; ++i){
    compute_tile(0);                                   // tile 2i   (buf0)
    stage(A, m0, (2 * i + 2) * 64, As[0]);             // tile 2i+2 -> buf0 (free now)
    stage(B, n0, (2 * i + 2) * 64, Bs[0]);
    asm volatile("s_waitcnt vmcnt(8)" ::: "memory");   // tile 2i+1 landed; 2i+2 in flight
    asm volatile("" ::: "memory");
    __builtin_amdgcn_s_barrier();
    asm volatile("" ::: "memory");
    compute_tile(1);                                   // tile 2i+1 (buf1)
    stage(A, m0, (2 * i + 3) * 64, As[1]);             // tile 2i+3 -> buf1
    stage(B, n0, (2 * i + 3) * 64, Bs[1]);
    asm volatile("s_waitcnt vmcnt(8)" ::: "memory");   // tile 2i+2 landed; 2i+3 in flight
    asm volatile("" ::: "memory");
    __builtin_amdgcn_s_barrier();
    asm volatile("" ::: "memory");
  }
  compute_tile(0);                                     // tile NT-2
  asm volatile("s_waitcnt vmcnt(0)" ::: "memory");     // drain last tile (epilogue only)
  __builtin_amdgcn_s_barrier();
  asm volatile("" ::: "memory");
  compute_tile(1);                                     // tile NT-1

  // epilogue
#pragma unroll
  for (int f = 0; f < 8; ++f){
    const int rowb = m0 + wr * 128 + f * 16 + ((l >> 4) << 2);
#pragma unroll
    for (int g = 0; g < 4; ++g){
      const int col = n0 + wc * 64 + g * 16 + (l & 15);
      const float bv = bias[col], gv = gate[col];
#pragma unroll
      for (int j = 0; j < 4; ++j){
        const int row = rowb + j;
        float v = acc[f][g][j] + bv;
        float gl = gelu_exact(v) * gv;
        if (MODE == 0){
          ((u16*)Cout)[(size_t)row * NDIM + col] = f2bf(gl);
        } else {
          size_t off = (size_t)row * NDIM + col;
          ((float*)Cout)[off] = xres[off] + gl;
        }
      }
    }
  }
}

// ---------------- launcher ----------------
extern "C" void kernel_launch(void* const* d_in, const int* in_sizes, int n_in,
                              void* d_out, int out_size, void* d_ws, size_t ws_size,
                              hipStream_t stream)
{
  const float* x       = (const float*)d_in[0];
  const int*   t       = (const int*)  d_in[1];
  const float* s       = (const float*)d_in[2];
  const float* fc1_w   = (const float*)d_in[3];
  const float* fc1_b   = (const float*)d_in[4];
  const float* fc2_w   = (const float*)d_in[5];
  const float* fc2_b   = (const float*)d_in[6];
  const float* efc1    = (const float*)d_in[7];
  const float* efc2    = (const float*)d_in[8];
  const float* sem_w   = (const float*)d_in[9];
  const float* sem_b   = (const float*)d_in[10];
  const float* rw      = (const float*)d_in[11];
  const float* larger_w= (const float*)d_in[12];
  const float* larger_b= (const float*)d_in[13];
  const float* elarger = (const float*)d_in[14];

  char* ws = (char*)d_ws;
  float* vote    = (float*)(ws + 0);         //  589824 B  [3][16384][3] f32
  float* gfc1p   = (float*)(ws + 589824);    //    8192 B  [2048]
  float* b1p     = (float*)(ws + 598016);    //    8192 B  [2048]
  float* gfc2    = (float*)(ws + 606208);    //    3072 B  [768]
  float* glarger = (float*)(ws + 609280);    //    3072 B  [768]
  u16*   Bw1     = (u16*)  (ws + 612352);    // 3145728 B  [2048][768] bf16
  u16*   Bw2     = (u16*)  (ws + 3758080);   // 3145728 B  [768][2048] bf16
  u16*   hpre    = (u16*)  (ws + 6903808);   // 25165824 B [16384][768] bf16
  u16*   Hm      = (u16*)  (ws + 32069632);  // 67108864 B [16384][2048] bf16
  // total 99,178,496 B

  prep_gates<<<8, 256, 0, stream>>>(s, t, efc1, efc2, elarger, fc1_b, gfc1p, b1p, gfc2, glarger);
  conv_w1<<<6144, 256, 0, stream>>>(fc1_w, Bw1);
  conv_w2<<<6144, 256, 0, stream>>>(fc2_w, Bw2);
  sem_route<<<1024, 256, 0, stream>>>(x, t, sem_w, sem_b, rw, vote);
  hpre_kernel<<<49152, 256, 0, stream>>>(x, vote, larger_w, larger_b, glarger, hpre);
  gemm8<0, 2048, 768><<<512, 512, 0, stream>>>(hpre, Bw1, b1p, gfc1p, nullptr, (void*)Hm, 8);
  gemm8<1, 768, 2048><<<192, 512, 0, stream>>>(Hm, Bw2, fc2_b, gfc2, x, d_out, 3);
}